// Round 3
// baseline (266.379 us; speedup 1.0000x reference)
//
#include <hip/hip_runtime.h>
#include <hip/hip_bf16.h>
#include <cmath>

#define Bsz 8
#define Csz 512
#define Lsz 4096
#define LPOOL 511
#define NEGV -1000000000.0f

typedef __attribute__((ext_vector_type(8))) short short8;
typedef __attribute__((ext_vector_type(4))) float float4v;

__device__ __forceinline__ float bf2f(short u) {
  unsigned int x = ((unsigned int)(unsigned short)u) << 16;
  return __builtin_bit_cast(float, x);
}

// fast tanh: 1 - 2/(e^{2x}+1); rel err ~1e-5, far below bf16 gemm noise
__device__ __forceinline__ float ftanh(float x) {
  float e = __expf(2.0f * x);
  return 1.0f - 2.0f * __builtin_amdgcn_rcpf(e + 1.0f);
}

// ---------------------------------------------------------------------------
// prep: block 0 = mask-width detect; blocks 1..128 = W f32 -> Wts bf16 tiled.
__global__ __launch_bounds__(256) void prep(const unsigned char* __restrict__ mb,
    int* __restrict__ flag, const float* __restrict__ W,
    __hip_bfloat16* __restrict__ Wts) {
  const int tid = threadIdx.x;
  const int pb = blockIdx.x;
  if (pb == 0) {
    __shared__ int sf;
    if (tid == 0) sf = 0;
    __syncthreads();
    int f = 0;
    for (int i = tid; i < 4096; i += 256)
      if ((i & 3) && mb[i]) f = 1;
    if (f) atomicOr(&sf, 1);
    __syncthreads();
    if (tid == 0) *flag = sf;  // 0 = int32 mask, 1 = uint8 mask
  } else {
    int tg = (pb - 1) * 256 + tid;
    int d = tg >> 6, cg = tg & 63;
    float4 w0 = *(const float4*)(W + (size_t)d * 512 + cg * 8);
    float4 w1 = *(const float4*)(W + (size_t)d * 512 + cg * 8 + 4);
    __hip_bfloat16 hb[8];
    hb[0] = __float2bfloat16(w0.x); hb[1] = __float2bfloat16(w0.y);
    hb[2] = __float2bfloat16(w0.z); hb[3] = __float2bfloat16(w0.w);
    hb[4] = __float2bfloat16(w1.x); hb[5] = __float2bfloat16(w1.y);
    hb[6] = __float2bfloat16(w1.z); hb[7] = __float2bfloat16(w1.w);
    int nt = d >> 7, row = d & 127, ks = cg >> 2, seg = cg & 3;
    *(short8*)(Wts + (((size_t)nt * 16 + ks) * 512 + seg * 128 + row) * 8) = *(short8*)hb;
  }
}

// ---------------------------------------------------------------------------
// gemm_fused v3: 2048 one-wave blocks (64 thr), 16 m-rows each. No barriers
// anywhere. Phase 1: per-wave LDS transpose of x (16 chunks of 32 c), keeps
// the MFMA A-fragments in REGISTERS (af[16] = 64 VGPR; lane (kseg,ll) already
// holds exactly the frag MFMA needs) and writes xbf as side product.
// Phase 2: 4 nt x 16 ks; B-fragments loaded straight from L2-resident Wts to
// registers (no LDS, no staging sync); acc -> tanh -> v-dot in registers;
// s stored directly (wave owns its 16 m rows; full K,N per wave).
__global__ __launch_bounds__(64, 2) void gemm_fused(
    const float* __restrict__ x, const __hip_bfloat16* __restrict__ Wts,
    const float* __restrict__ bias, const float* __restrict__ v,
    float* __restrict__ s, __hip_bfloat16* __restrict__ xbf) {
  __shared__ float sX[32][17];                 // 2.2 KiB; 17 pitch (2-way max)

  const int lane = threadIdx.x;                // 0..63, one wave per block
  const int mt = blockIdx.x;                   // 0..2047
  const int b = mt >> 8;
  const int l0 = (mt & 255) << 4;              // 16 l-rows per block

  short8 af[16];                               // A-frags: 16 k-steps, 64 VGPR

  // ---------------- phase 1: transpose x -> af registers + xbf --------------
  {
    const int r = lane >> 1;                   // c-row within 32-c chunk
    const int q = lane & 1;                    // 8-float half of the 16 l's
    const size_t rowbase =
        (((size_t)(b * Csz + r)) << 12) + (size_t)(l0 + q * 8);
    const float* xg = x + rowbase;
    const int ll = lane & 15, kseg = lane >> 4;

    float4 a0 = *(const float4*)(xg);
    float4 a1 = *(const float4*)(xg + 4);
    float4 b0 = *(const float4*)(xg + (1u << 17));
    float4 b1 = *(const float4*)(xg + (1u << 17) + 4);
    float4 c0 = a0, c1 = a1;

    #pragma unroll
    for (int cc = 0; cc < 16; ++cc) {
      if (cc < 14) {
        const float* xn = xg + ((size_t)(cc + 2) << 17);
        c0 = *(const float4*)(xn);
        c1 = *(const float4*)(xn + 4);
      }
      __hip_bfloat16 hb[8];
      hb[0] = __float2bfloat16(a0.x); hb[1] = __float2bfloat16(a0.y);
      hb[2] = __float2bfloat16(a0.z); hb[3] = __float2bfloat16(a0.w);
      hb[4] = __float2bfloat16(a1.x); hb[5] = __float2bfloat16(a1.y);
      hb[6] = __float2bfloat16(a1.z); hb[7] = __float2bfloat16(a1.w);
      *(short8*)(xbf + rowbase + ((size_t)cc << 17)) = *(short8*)hb;
      *(float4*)(&sX[r][q * 8])     = a0;
      *(float4*)(&sX[r][q * 8 + 4]) = a1;
      asm volatile("s_waitcnt lgkmcnt(0)" ::: "memory");  // cross-lane vis
      __builtin_amdgcn_sched_barrier(0);
      float tv[8];
      #pragma unroll
      for (int j = 0; j < 8; ++j) tv[j] = sX[kseg * 8 + j][ll];
      __hip_bfloat16 ab[8];
      #pragma unroll
      for (int j = 0; j < 8; ++j) ab[j] = __float2bfloat16(tv[j]);
      af[cc] = *(short8*)ab;                   // static index: stays in VGPRs
      asm volatile("s_waitcnt lgkmcnt(0)" ::: "memory");  // reads before reuse
      __builtin_amdgcn_sched_barrier(0);
      a0 = b0; a1 = b1; b0 = c0; b1 = c1;
    }
  }

  // ---------------- phase 2: B from global (L2), no sync --------------------
  const int lr = lane & 15, quad = lane >> 4;
  float sp[4] = {0.f, 0.f, 0.f, 0.f};
  const short8* Wt8 = (const short8*)Wts;

  for (int nt = 0; nt < 4; ++nt) {
    float bl[8], vl[8];
    #pragma unroll
    for (int nf = 0; nf < 8; ++nf) {
      int n = nt * 128 + nf * 16 + lr;
      bl[nf] = bias[n];
      vl[nf] = v[n];
    }
    float4v acc[8];
    #pragma unroll
    for (int nf = 0; nf < 8; ++nf) acc[nf] = (float4v)0.f;

    #pragma unroll
    for (int ks = 0; ks < 16; ++ks) {
      const short8* bt = Wt8 + ((size_t)(nt * 16 + ks) * 512 + quad * 128 + lr);
      short8 bfr[8];
      #pragma unroll
      for (int nf = 0; nf < 8; ++nf) bfr[nf] = bt[nf * 16];
      #pragma unroll
      for (int nf = 0; nf < 8; ++nf)
        acc[nf] = __builtin_amdgcn_mfma_f32_16x16x32_bf16(
            af[ks], bfr[nf], acc[nf], 0, 0, 0);
    }

    // epilogue for this nt (overlaps next nt's loads; no sync needed)
    #pragma unroll
    for (int reg = 0; reg < 4; ++reg) {
      float pp = 0.f;
      #pragma unroll
      for (int nf = 0; nf < 8; ++nf)
        pp += ftanh(acc[nf][reg] + bl[nf]) * vl[nf];
      sp[reg] += pp;
    }
  }

  // reduce over the 16 n-lanes and store s directly (no atomics)
  #pragma unroll
  for (int reg = 0; reg < 4; ++reg) {
    float pv = sp[reg];
    pv += __shfl_xor(pv, 1, 16);
    pv += __shfl_xor(pv, 2, 16);
    pv += __shfl_xor(pv, 4, 16);
    pv += __shfl_xor(pv, 8, 16);
    if (lr == 0)
      s[mt * 16 + quad * 4 + reg] = pv;
  }
}

// ---------------------------------------------------------------------------
// pool2: fused windowed-softmax + pooling. z-split over c halves for 2x TLP.
__global__ __launch_bounds__(256) void pool2(const __hip_bfloat16* __restrict__ xbf,
    const float* __restrict__ s, const void* __restrict__ mask,
    const int* __restrict__ flag, float* __restrict__ out) {
  __shared__ float wl[8][17];
  const int t = threadIdx.x;
  const int p0 = blockIdx.x * 8, b = blockIdx.y;
  const int ch = blockIdx.z;
  if (t < 8 && p0 + t < LPOOL) {
    const int p = p0 + t;
    const bool u8 = (*flag != 0);
    const unsigned char* m8 = (const unsigned char*)mask;
    const int* m32 = (const int*)mask;
    const int base = b * Lsz + p * 8;
    float sv[16]; int mv[16];
    float mx = -3.4e38f;
    #pragma unroll
    for (int w = 0; w < 16; ++w) {
      int mk = u8 ? (int)m8[base + w] : m32[base + w];
      float val = mk ? NEGV : s[base + w];
      sv[w] = val; mv[w] = mk;
      mx = fmaxf(mx, val);
    }
    float sum = 0.f;
    #pragma unroll
    for (int w = 0; w < 16; ++w) { sv[w] = expf(sv[w] - mx); sum += sv[w]; }
    float inv = 1.0f / sum;
    float norm = 0.f;
    #pragma unroll
    for (int w = 0; w < 16; ++w) { sv[w] = mv[w] ? 0.f : sv[w] * inv; norm += sv[w]; }
    norm = fmaxf(norm, 1e-6f);
    float rn = 1.0f / norm;
    #pragma unroll
    for (int w = 0; w < 16; ++w) wl[t][w] = sv[w] * rn;
  }
  __syncthreads();
  const int ci = t >> 3, pi = t & 7;
  const int p = p0 + pi;
  if (p >= LPOOL) return;
  float wr[16];
  #pragma unroll
  for (int w = 0; w < 16; ++w) wr[w] = wl[pi][w];
  #pragma unroll
  for (int it = 0; it < 8; ++it) {
    int c = ch * 256 + it * 32 + ci;
    const __hip_bfloat16* xp = xbf + ((size_t)b * Csz + c) * Lsz + 8 * p;
    short8 lo = *(const short8*)xp;
    short8 hi = *(const short8*)(xp + 8);
    float acc = 0.f;
    #pragma unroll
    for (int j = 0; j < 8; ++j)
      acc += bf2f(lo[j]) * wr[j] + bf2f(hi[j]) * wr[8 + j];
    out[((size_t)b * Csz + c) * LPOOL + p] = acc;
  }
}

// ---------------------------------------------------------------------------
// Fallback path kernels (only if ws too small for bf16 path)
__global__ void detect_mask(const unsigned char* __restrict__ mb, int* __restrict__ flag) {
  __shared__ int sf;
  int t = threadIdx.x;
  if (t == 0) sf = 0;
  __syncthreads();
  int f = 0;
  for (int i = t; i < 4096; i += 256)
    if ((i & 3) && mb[i]) f = 1;
  if (f) atomicOr(&sf, 1);
  __syncthreads();
  if (t == 0) *flag = sf;
}

__global__ __launch_bounds__(256) void gemm_s_f32(const float* __restrict__ x,
    const float* __restrict__ W, const float* __restrict__ bias,
    const float* __restrict__ v, float* __restrict__ s_out) {
  __shared__ float sA[32][64];
  __shared__ float sB[32][68];
  __shared__ float s_acc[64];
  const int tid = threadIdx.x;
  const int b = blockIdx.y;
  const int l0 = blockIdx.x * 64;
  if (tid < 64) s_acc[tid] = 0.0f;
  const int tx = tid & 15;
  const int ty = tid >> 4;
  const float* xb = x + ((size_t)b * Csz) * Lsz + l0;
  for (int d0 = 0; d0 < Csz; d0 += 64) {
    float acc[4][4] = {{0.f}};
    for (int c0 = 0; c0 < Csz; c0 += 32) {
      __syncthreads();
      #pragma unroll
      for (int it = 0; it < 8; ++it) {
        int idx = tid + it * 256;
        int kc = idx >> 6, ml = idx & 63;
        sA[kc][ml] = xb[(size_t)(c0 + kc) * Lsz + ml];
      }
      #pragma unroll
      for (int it = 0; it < 8; ++it) {
        int idx = tid + it * 256;
        int kc = idx & 31, dj = idx >> 5;
        sB[kc][dj] = W[(size_t)(d0 + dj) * Csz + c0 + kc];
      }
      __syncthreads();
      #pragma unroll
      for (int kc = 0; kc < 32; ++kc) {
        float4 a  = *(const float4*)(&sA[kc][tx << 2]);
        float4 w4 = *(const float4*)(&sB[kc][ty << 2]);
        acc[0][0] += a.x * w4.x; acc[0][1] += a.x * w4.y; acc[0][2] += a.x * w4.z; acc[0][3] += a.x * w4.w;
        acc[1][0] += a.y * w4.x; acc[1][1] += a.y * w4.y; acc[1][2] += a.y * w4.z; acc[1][3] += a.y * w4.w;
        acc[2][0] += a.z * w4.x; acc[2][1] += a.z * w4.y; acc[2][2] += a.z * w4.z; acc[2][3] += a.z * w4.w;
        acc[3][0] += a.w * w4.x; acc[3][1] += a.w * w4.y; acc[3][2] += a.w * w4.z; acc[3][3] += a.w * w4.w;
      }
    }
    float part[4] = {0.f, 0.f, 0.f, 0.f};
    #pragma unroll
    for (int j = 0; j < 4; ++j) {
      int d = d0 + (ty << 2) + j;
      float bj = bias[d], vj = v[d];
      #pragma unroll
      for (int i = 0; i < 4; ++i)
        part[i] += tanhf(acc[i][j] + bj) * vj;
    }
    #pragma unroll
    for (int i = 0; i < 4; ++i)
      atomicAdd(&s_acc[(tx << 2) + i], part[i]);
  }
  __syncthreads();
  if (tid < 64) s_out[(size_t)b * Lsz + l0 + tid] = s_acc[tid];
}

__global__ void win_weights(const float* __restrict__ s, const void* __restrict__ mask,
                            const int* __restrict__ flag, float* __restrict__ wgt) {
  int t = blockIdx.x * blockDim.x + threadIdx.x;
  if (t >= Bsz * LPOOL) return;
  int b = t / LPOOL, p = t - b * LPOOL;
  const bool u8 = (*flag != 0);
  const unsigned char* m8 = (const unsigned char*)mask;
  const int* m32 = (const int*)mask;
  float sv[16]; int mv[16];
  float mx = -3.4e38f;
  int base = b * Lsz + p * 8;
  #pragma unroll
  for (int w = 0; w < 16; ++w) {
    int mk = u8 ? (int)m8[base + w] : m32[base + w];
    float val = mk ? NEGV : s[base + w];
    sv[w] = val; mv[w] = mk;
    mx = fmaxf(mx, val);
  }
  float sum = 0.f;
  #pragma unroll
  for (int w = 0; w < 16; ++w) { sv[w] = expf(sv[w] - mx); sum += sv[w]; }
  float inv = 1.0f / sum;
  float norm = 0.f;
  #pragma unroll
  for (int w = 0; w < 16; ++w) { sv[w] = mv[w] ? 0.f : sv[w] * inv; norm += sv[w]; }
  norm = fmaxf(norm, 1e-6f);
  float rn = 1.0f / norm;
  #pragma unroll
  for (int w = 0; w < 16; ++w) wgt[t * 16 + w] = sv[w] * rn;
}

__global__ __launch_bounds__(256) void pool_out(const float* __restrict__ x,
    const float* __restrict__ wgt, float* __restrict__ out) {
  __shared__ float xrow[Lsz];
  int bc = blockIdx.x;
  int c = bc & (Csz - 1);
  int b = bc >> 9;
  const float* xr = x + ((size_t)b * Csz + c) * Lsz;
  int tid = threadIdx.x;
  #pragma unroll
  for (int it = 0; it < 4; ++it) {
    int idx = (tid + it * 256) << 2;
    *(float4*)(&xrow[idx]) = *(const float4*)(&xr[idx]);
  }
  __syncthreads();
  const float* wb = wgt + (size_t)b * LPOOL * 16;
  float* ob = out + ((size_t)b * Csz + c) * LPOOL;
  for (int p = tid; p < LPOOL; p += 256) {
    const float4* wp = (const float4*)(wb + p * 16);
    const float4* xp = (const float4*)(&xrow[p * 8]);
    float acc = 0.f;
    #pragma unroll
    for (int q = 0; q < 4; ++q) {
      float4 wv = wp[q], xv = xp[q];
      acc += xv.x * wv.x + xv.y * wv.y + xv.z * wv.z + xv.w * wv.w;
    }
    ob[p] = acc;
  }
}

// ---------------------------------------------------------------------------
extern "C" void kernel_launch(void* const* d_in, const int* in_sizes, int n_in,
                              void* d_out, int out_size, void* d_ws, size_t ws_size,
                              hipStream_t stream) {
  const float* x    = (const float*)d_in[0];
  const void*  mask = d_in[1];
  const float* W    = (const float*)d_in[2];
  const float* bias = (const float*)d_in[3];
  const float* v    = (const float*)d_in[4];
  float* out = (float*)d_out;

  char* wsb = (char*)d_ws;
  int*   flag = (int*)wsb;                                   // 256 B
  float* s    = (float*)(wsb + 256);                         // 131072 B
  float* wgt  = (float*)(wsb + 131328);                      // 261632 B (fallback only)
  __hip_bfloat16* Wts = (__hip_bfloat16*)(wsb + 393216);     // 524288 B
  __hip_bfloat16* xbf = (__hip_bfloat16*)(wsb + 917504);     // 32 MiB
  const size_t NEED = 917504 + 33554432;

  if (ws_size >= NEED) {
    prep<<<129, 256, 0, stream>>>((const unsigned char*)mask, flag, W, Wts);
    gemm_fused<<<2048, 64, 0, stream>>>(x, Wts, bias, v, s, xbf);
    pool2<<<dim3(64, Bsz, 2), 256, 0, stream>>>(xbf, s, mask, flag, out);
  } else {
    detect_mask<<<1, 256, 0, stream>>>((const unsigned char*)mask, flag);
    gemm_s_f32<<<dim3(Lsz / 64, Bsz), 256, 0, stream>>>(x, W, bias, v, s);
    win_weights<<<(Bsz * LPOOL + 255) / 256, 256, 0, stream>>>(s, mask, flag, wgt);
    pool_out<<<Bsz * Csz, 256, 0, stream>>>(x, wgt, out);
  }
}

// Round 4
// 159.742 us; speedup vs baseline: 1.6676x; 1.6676x over previous
//
#include <hip/hip_runtime.h>
#include <hip/hip_bf16.h>
#include <cmath>

#define Bsz 8
#define Csz 512
#define Lsz 4096
#define LPOOL 511
#define NEGV -1000000000.0f

typedef __attribute__((ext_vector_type(8))) short short8;
typedef __attribute__((ext_vector_type(4))) float float4v;

__device__ __forceinline__ float bf2f(short u) {
  unsigned int x = ((unsigned int)(unsigned short)u) << 16;
  return __builtin_bit_cast(float, x);
}

// fast tanh: 1 - 2/(e^{2x}+1); rel err ~1e-5, far below bf16 gemm noise
__device__ __forceinline__ float ftanh(float x) {
  float e = __expf(2.0f * x);
  return 1.0f - 2.0f * __builtin_amdgcn_rcpf(e + 1.0f);
}

// async global->LDS, 16B per lane; LDS dest = wave-uniform base + lane*16 (HW)
__device__ __forceinline__ void gl_lds16(const __hip_bfloat16* g, void* l) {
  __builtin_amdgcn_global_load_lds(
      (const __attribute__((address_space(1))) unsigned int*)g,
      (__attribute__((address_space(3))) unsigned int*)l, 16, 0, 0);
}

// ---------------------------------------------------------------------------
// prep: block 0 = mask-width detect; blocks 1..128 = W f32 -> Wts bf16 tiled.
__global__ __launch_bounds__(256) void prep(const unsigned char* __restrict__ mb,
    int* __restrict__ flag, const float* __restrict__ W,
    __hip_bfloat16* __restrict__ Wts) {
  const int tid = threadIdx.x;
  const int pb = blockIdx.x;
  if (pb == 0) {
    __shared__ int sf;
    if (tid == 0) sf = 0;
    __syncthreads();
    int f = 0;
    for (int i = tid; i < 4096; i += 256)
      if ((i & 3) && mb[i]) f = 1;
    if (f) atomicOr(&sf, 1);
    __syncthreads();
    if (tid == 0) *flag = sf;  // 0 = int32 mask, 1 = uint8 mask
  } else {
    int tg = (pb - 1) * 256 + tid;
    int d = tg >> 6, cg = tg & 63;
    float4 w0 = *(const float4*)(W + (size_t)d * 512 + cg * 8);
    float4 w1 = *(const float4*)(W + (size_t)d * 512 + cg * 8 + 4);
    __hip_bfloat16 hb[8];
    hb[0] = __float2bfloat16(w0.x); hb[1] = __float2bfloat16(w0.y);
    hb[2] = __float2bfloat16(w0.z); hb[3] = __float2bfloat16(w0.w);
    hb[4] = __float2bfloat16(w1.x); hb[5] = __float2bfloat16(w1.y);
    hb[6] = __float2bfloat16(w1.z); hb[7] = __float2bfloat16(w1.w);
    int nt = d >> 7, row = d & 127, ks = cg >> 2, seg = cg & 3;
    *(short8*)(Wts + (((size_t)nt * 16 + ks) * 512 + seg * 128 + row) * 8) = *(short8*)hb;
  }
}

// ---------------------------------------------------------------------------
// gemm_fused v4: 512 blocks x 256 thr (4 waves), 64 m-rows/block, LDS = 80 KiB
// exactly -> 2 blocks/CU (independent blocks hide each other's stalls).
// Phase 1: per-wave register transpose of x (wave owns 16 l-rows) -> sA
// (MFMA-tiled, 64 KiB) + xbf side-product. Phase 2: wave tile 32m x 64n
// (6 ds_read_b128 per 8 MFMA, 33% less LDS traffic than R2's 9/8); B tile
// double-buffered via global_load_lds, counted vmcnt(2); per-nt tanh epilogue
// in registers; final cross-nh reduce through 256 B of dead sB space.
__global__ __launch_bounds__(256, 2) void gemm_fused(
    const float* __restrict__ x, const __hip_bfloat16* __restrict__ Wts,
    const float* __restrict__ bias, const float* __restrict__ v,
    float* __restrict__ s, __hip_bfloat16* __restrict__ xbf) {
  __shared__ short8 sA[4096];                    // 64 KiB: A 64m x 512k tiled
  __shared__ __align__(16) char sPool[16384];    // union: sB[2][512] / sX / sRed

  const int tid = threadIdx.x;
  const int lane = tid & 63, wave = tid >> 6;
  const int mt = blockIdx.x;                     // 0..511
  const int b = mt >> 6;
  const int l0 = (mt & 63) << 6;                 // 64 l-rows per block

  // ---------------- phase 1: per-wave transpose, no block barriers ----------
  {
    float* sXw = (float*)sPool + wave * 544;     // [32 c][17 pitch] per wave
    const int r = lane >> 1;                     // c-row within 32-c chunk
    const int q = lane & 1;                      // 8-float half of wave's 16 l
    const size_t rowbase =
        (((size_t)(b * Csz + r)) << 12) + (size_t)(l0 + wave * 16 + q * 8);
    const float* xg = x + rowbase;
    const int ll = lane & 15, kseg = lane >> 4;

    float4 a0 = *(const float4*)(xg);
    float4 a1 = *(const float4*)(xg + 4);
    float4 b0 = *(const float4*)(xg + (1u << 17));
    float4 b1 = *(const float4*)(xg + (1u << 17) + 4);
    float4 c0 = a0, c1 = a1;

    for (int cc = 0; cc < 16; ++cc) {
      if (cc < 14) {
        const float* xn = xg + ((size_t)(cc + 2) << 17);
        c0 = *(const float4*)(xn);
        c1 = *(const float4*)(xn + 4);
      }
      // current chunk -> bf16 xbf store + f32 LDS stage
      __hip_bfloat16 hb[8];
      hb[0] = __float2bfloat16(a0.x); hb[1] = __float2bfloat16(a0.y);
      hb[2] = __float2bfloat16(a0.z); hb[3] = __float2bfloat16(a0.w);
      hb[4] = __float2bfloat16(a1.x); hb[5] = __float2bfloat16(a1.y);
      hb[6] = __float2bfloat16(a1.z); hb[7] = __float2bfloat16(a1.w);
      *(short8*)(xbf + rowbase + ((size_t)cc << 17)) = *(short8*)hb;
      *(float4*)(&sXw[r * 17 + q * 8])     = a0;
      *(float4*)(&sXw[r * 17 + q * 8 + 4]) = a1;
      asm volatile("s_waitcnt lgkmcnt(0)" ::: "memory");  // wave-lockstep vis
      __builtin_amdgcn_sched_barrier(0);
      // transposed read: 8 consecutive c's for one l (2-way banks, free)
      float tv[8];
      #pragma unroll
      for (int j = 0; j < 8; ++j) tv[j] = sXw[(kseg * 8 + j) * 17 + ll];
      __hip_bfloat16 ab[8];
      #pragma unroll
      for (int j = 0; j < 8; ++j) ab[j] = __float2bfloat16(tv[j]);
      // k0 = cc*32 + kseg*8  ->  ks = cc, seg = kseg
      sA[(cc * 4 + kseg) * 64 + wave * 16 + ll] = *(short8*)ab;
      asm volatile("s_waitcnt lgkmcnt(0)" ::: "memory");  // reads done pre-reuse
      __builtin_amdgcn_sched_barrier(0);
      a0 = b0; a1 = b1; b0 = c0; b1 = c1;
    }
  }

  // wave tile: mh selects 32 m-rows, nh selects 64 n-cols within each nt
  const int lr = lane & 15, quad = lane >> 4;
  const int mh = wave >> 1, nh = wave & 1;

  // preload bias/v fragments (compile-time nt/nf indexing; stays in VGPRs)
  float bl[4][4], vl[4][4];
  #pragma unroll
  for (int nt = 0; nt < 4; ++nt)
    #pragma unroll
    for (int nf = 0; nf < 4; ++nf) {
      int n = nt * 128 + nh * 64 + nf * 16 + lr;
      bl[nt][nf] = bias[n];
      vl[nt][nf] = v[n];
    }

  __syncthreads();   // all sX use done -> sPool may be reused as sB
  short8 (*sB)[512] = (short8 (*)[512])sPool;
  // pre-stage B tile 0: 4 waves x 2 KB = full 8 KB tile
  {
    const __hip_bfloat16* gb = Wts + (size_t)(wave * 64 + lane) * 8;
    gl_lds16(gb,        &sB[0][wave * 64]);
    gl_lds16(gb + 2048, &sB[0][256 + wave * 64]);
  }
  __syncthreads();   // vmcnt(0)+lgkmcnt(0) drain -> exact vm counting below

  // ---------------- phase 2: nt-loop with A resident ------------------------
  float sp[2][4];
  #pragma unroll
  for (int mf = 0; mf < 2; ++mf)
    #pragma unroll
    for (int reg = 0; reg < 4; ++reg) sp[mf][reg] = 0.f;

  #pragma unroll
  for (int nt = 0; nt < 4; ++nt) {
    float4v acc[2][4];
    #pragma unroll
    for (int mf = 0; mf < 2; ++mf)
      #pragma unroll
      for (int nf = 0; nf < 4; ++nf) acc[mf][nf] = (float4v)0.f;

    #pragma unroll 2
    for (int ks = 0; ks < 16; ++ks) {
      const int idx = nt * 16 + ks;
      const int cur = idx & 1;
      if (idx < 63) {
        const __hip_bfloat16* gb =
            Wts + ((size_t)(idx + 1) << 12) + (size_t)(wave * 64 + lane) * 8;
        gl_lds16(gb,        &sB[cur ^ 1][wave * 64]);
        gl_lds16(gb + 2048, &sB[cur ^ 1][256 + wave * 64]);
        asm volatile("s_waitcnt vmcnt(2)" ::: "memory");  // cur tile landed
      } else {
        asm volatile("s_waitcnt vmcnt(0)" ::: "memory");
      }
      __builtin_amdgcn_sched_barrier(0);
      __builtin_amdgcn_s_barrier();        // all waves' portions visible
      short8 af[2], bfr[4];
      #pragma unroll
      for (int mf = 0; mf < 2; ++mf)
        af[mf] = sA[(ks * 4 + quad) * 64 + mh * 32 + mf * 16 + lr];
      #pragma unroll
      for (int nf = 0; nf < 4; ++nf)
        bfr[nf] = sB[cur][quad * 128 + nh * 64 + nf * 16 + lr];
      __builtin_amdgcn_s_setprio(1);
      #pragma unroll
      for (int mf = 0; mf < 2; ++mf)
        #pragma unroll
        for (int nf = 0; nf < 4; ++nf)
          acc[mf][nf] = __builtin_amdgcn_mfma_f32_16x16x32_bf16(
              af[mf], bfr[nf], acc[mf][nf], 0, 0, 0);
      __builtin_amdgcn_s_setprio(0);
      __builtin_amdgcn_s_barrier();        // reads done before next stage lands
    }
    // epilogue for this nt: overlaps next nt's in-flight B stage
    #pragma unroll
    for (int mf = 0; mf < 2; ++mf)
      #pragma unroll
      for (int reg = 0; reg < 4; ++reg) {
        float pp = 0.f;
        #pragma unroll
        for (int nf = 0; nf < 4; ++nf)
          pp += ftanh(acc[mf][nf][reg] + bl[nt][nf]) * vl[nt][nf];
        sp[mf][reg] += pp;
      }
  }

  // reduce over the 16 n-lanes; combine the two nh waves via dead sB space
  float* sRed = (float*)sPool;             // [mh][mf][quad][reg] = 64 floats
  float pv[2][4];
  #pragma unroll
  for (int mf = 0; mf < 2; ++mf)
    #pragma unroll
    for (int reg = 0; reg < 4; ++reg) {
      float p = sp[mf][reg];
      p += __shfl_xor(p, 1, 16);
      p += __shfl_xor(p, 2, 16);
      p += __shfl_xor(p, 4, 16);
      p += __shfl_xor(p, 8, 16);
      pv[mf][reg] = p;
    }
  if (nh == 1 && lr == 0) {
    #pragma unroll
    for (int mf = 0; mf < 2; ++mf)
      #pragma unroll
      for (int reg = 0; reg < 4; ++reg)
        sRed[((mh * 2 + mf) * 4 + quad) * 4 + reg] = pv[mf][reg];
  }
  __syncthreads();
  if (nh == 0 && lr == 0) {
    #pragma unroll
    for (int mf = 0; mf < 2; ++mf)
      #pragma unroll
      for (int reg = 0; reg < 4; ++reg)
        s[mt * 64 + mh * 32 + mf * 16 + quad * 4 + reg] =
            pv[mf][reg] + sRed[((mh * 2 + mf) * 4 + quad) * 4 + reg];
  }
}

// ---------------------------------------------------------------------------
// pool2: fused windowed-softmax + pooling. z-split over c halves for 2x TLP.
__global__ __launch_bounds__(256) void pool2(const __hip_bfloat16* __restrict__ xbf,
    const float* __restrict__ s, const void* __restrict__ mask,
    const int* __restrict__ flag, float* __restrict__ out) {
  __shared__ float wl[8][17];
  const int t = threadIdx.x;
  const int p0 = blockIdx.x * 8, b = blockIdx.y;
  const int ch = blockIdx.z;
  if (t < 8 && p0 + t < LPOOL) {
    const int p = p0 + t;
    const bool u8 = (*flag != 0);
    const unsigned char* m8 = (const unsigned char*)mask;
    const int* m32 = (const int*)mask;
    const int base = b * Lsz + p * 8;
    float sv[16]; int mv[16];
    float mx = -3.4e38f;
    #pragma unroll
    for (int w = 0; w < 16; ++w) {
      int mk = u8 ? (int)m8[base + w] : m32[base + w];
      float val = mk ? NEGV : s[base + w];
      sv[w] = val; mv[w] = mk;
      mx = fmaxf(mx, val);
    }
    float sum = 0.f;
    #pragma unroll
    for (int w = 0; w < 16; ++w) { sv[w] = expf(sv[w] - mx); sum += sv[w]; }
    float inv = 1.0f / sum;
    float norm = 0.f;
    #pragma unroll
    for (int w = 0; w < 16; ++w) { sv[w] = mv[w] ? 0.f : sv[w] * inv; norm += sv[w]; }
    norm = fmaxf(norm, 1e-6f);
    float rn = 1.0f / norm;
    #pragma unroll
    for (int w = 0; w < 16; ++w) wl[t][w] = sv[w] * rn;
  }
  __syncthreads();
  const int ci = t >> 3, pi = t & 7;
  const int p = p0 + pi;
  if (p >= LPOOL) return;
  float wr[16];
  #pragma unroll
  for (int w = 0; w < 16; ++w) wr[w] = wl[pi][w];
  #pragma unroll
  for (int it = 0; it < 8; ++it) {
    int c = ch * 256 + it * 32 + ci;
    const __hip_bfloat16* xp = xbf + ((size_t)b * Csz + c) * Lsz + 8 * p;
    short8 lo = *(const short8*)xp;
    short8 hi = *(const short8*)(xp + 8);
    float acc = 0.f;
    #pragma unroll
    for (int j = 0; j < 8; ++j)
      acc += bf2f(lo[j]) * wr[j] + bf2f(hi[j]) * wr[8 + j];
    out[((size_t)b * Csz + c) * LPOOL + p] = acc;
  }
}

// ---------------------------------------------------------------------------
// Fallback path kernels (only if ws too small for bf16 path)
__global__ void detect_mask(const unsigned char* __restrict__ mb, int* __restrict__ flag) {
  __shared__ int sf;
  int t = threadIdx.x;
  if (t == 0) sf = 0;
  __syncthreads();
  int f = 0;
  for (int i = t; i < 4096; i += 256)
    if ((i & 3) && mb[i]) f = 1;
  if (f) atomicOr(&sf, 1);
  __syncthreads();
  if (t == 0) *flag = sf;
}

__global__ __launch_bounds__(256) void gemm_s_f32(const float* __restrict__ x,
    const float* __restrict__ W, const float* __restrict__ bias,
    const float* __restrict__ v, float* __restrict__ s_out) {
  __shared__ float sA[32][64];
  __shared__ float sB[32][68];
  __shared__ float s_acc[64];
  const int tid = threadIdx.x;
  const int b = blockIdx.y;
  const int l0 = blockIdx.x * 64;
  if (tid < 64) s_acc[tid] = 0.0f;
  const int tx = tid & 15;
  const int ty = tid >> 4;
  const float* xb = x + ((size_t)b * Csz) * Lsz + l0;
  for (int d0 = 0; d0 < Csz; d0 += 64) {
    float acc[4][4] = {{0.f}};
    for (int c0 = 0; c0 < Csz; c0 += 32) {
      __syncthreads();
      #pragma unroll
      for (int it = 0; it < 8; ++it) {
        int idx = tid + it * 256;
        int kc = idx >> 6, ml = idx & 63;
        sA[kc][ml] = xb[(size_t)(c0 + kc) * Lsz + ml];
      }
      #pragma unroll
      for (int it = 0; it < 8; ++it) {
        int idx = tid + it * 256;
        int kc = idx & 31, dj = idx >> 5;
        sB[kc][dj] = W[(size_t)(d0 + dj) * Csz + c0 + kc];
      }
      __syncthreads();
      #pragma unroll
      for (int kc = 0; kc < 32; ++kc) {
        float4 a  = *(const float4*)(&sA[kc][tx << 2]);
        float4 w4 = *(const float4*)(&sB[kc][ty << 2]);
        acc[0][0] += a.x * w4.x; acc[0][1] += a.x * w4.y; acc[0][2] += a.x * w4.z; acc[0][3] += a.x * w4.w;
        acc[1][0] += a.y * w4.x; acc[1][1] += a.y * w4.y; acc[1][2] += a.y * w4.z; acc[1][3] += a.y * w4.w;
        acc[2][0] += a.z * w4.x; acc[2][1] += a.z * w4.y; acc[2][2] += a.z * w4.z; acc[2][3] += a.z * w4.w;
        acc[3][0] += a.w * w4.x; acc[3][1] += a.w * w4.y; acc[3][2] += a.w * w4.z; acc[3][3] += a.w * w4.w;
      }
    }
    float part[4] = {0.f, 0.f, 0.f, 0.f};
    #pragma unroll
    for (int j = 0; j < 4; ++j) {
      int d = d0 + (ty << 2) + j;
      float bj = bias[d], vj = v[d];
      #pragma unroll
      for (int i = 0; i < 4; ++i)
        part[i] += tanhf(acc[i][j] + bj) * vj;
    }
    #pragma unroll
    for (int i = 0; i < 4; ++i)
      atomicAdd(&s_acc[(tx << 2) + i], part[i]);
  }
  __syncthreads();
  if (tid < 64) s_out[(size_t)b * Lsz + l0 + tid] = s_acc[tid];
}

__global__ void win_weights(const float* __restrict__ s, const void* __restrict__ mask,
                            const int* __restrict__ flag, float* __restrict__ wgt) {
  int t = blockIdx.x * blockDim.x + threadIdx.x;
  if (t >= Bsz * LPOOL) return;
  int b = t / LPOOL, p = t - b * LPOOL;
  const bool u8 = (*flag != 0);
  const unsigned char* m8 = (const unsigned char*)mask;
  const int* m32 = (const int*)mask;
  float sv[16]; int mv[16];
  float mx = -3.4e38f;
  int base = b * Lsz + p * 8;
  #pragma unroll
  for (int w = 0; w < 16; ++w) {
    int mk = u8 ? (int)m8[base + w] : m32[base + w];
    float val = mk ? NEGV : s[base + w];
    sv[w] = val; mv[w] = mk;
    mx = fmaxf(mx, val);
  }
  float sum = 0.f;
  #pragma unroll
  for (int w = 0; w < 16; ++w) { sv[w] = expf(sv[w] - mx); sum += sv[w]; }
  float inv = 1.0f / sum;
  float norm = 0.f;
  #pragma unroll
  for (int w = 0; w < 16; ++w) { sv[w] = mv[w] ? 0.f : sv[w] * inv; norm += sv[w]; }
  norm = fmaxf(norm, 1e-6f);
  float rn = 1.0f / norm;
  #pragma unroll
  for (int w = 0; w < 16; ++w) wgt[t * 16 + w] = sv[w] * rn;
}

__global__ __launch_bounds__(256) void pool_out(const float* __restrict__ x,
    const float* __restrict__ wgt, float* __restrict__ out) {
  __shared__ float xrow[Lsz];
  int bc = blockIdx.x;
  int c = bc & (Csz - 1);
  int b = bc >> 9;
  const float* xr = x + ((size_t)b * Csz + c) * Lsz;
  int tid = threadIdx.x;
  #pragma unroll
  for (int it = 0; it < 4; ++it) {
    int idx = (tid + it * 256) << 2;
    *(float4*)(&xrow[idx]) = *(const float4*)(&xr[idx]);
  }
  __syncthreads();
  const float* wb = wgt + (size_t)b * LPOOL * 16;
  float* ob = out + ((size_t)b * Csz + c) * LPOOL;
  for (int p = tid; p < LPOOL; p += 256) {
    const float4* wp = (const float4*)(wb + p * 16);
    const float4* xp = (const float4*)(&xrow[p * 8]);
    float acc = 0.f;
    #pragma unroll
    for (int q = 0; q < 4; ++q) {
      float4 wv = wp[q], xv = xp[q];
      acc += xv.x * wv.x + xv.y * wv.y + xv.z * wv.z + xv.w * wv.w;
    }
    ob[p] = acc;
  }
}

// ---------------------------------------------------------------------------
extern "C" void kernel_launch(void* const* d_in, const int* in_sizes, int n_in,
                              void* d_out, int out_size, void* d_ws, size_t ws_size,
                              hipStream_t stream) {
  const float* x    = (const float*)d_in[0];
  const void*  mask = d_in[1];
  const float* W    = (const float*)d_in[2];
  const float* bias = (const float*)d_in[3];
  const float* v    = (const float*)d_in[4];
  float* out = (float*)d_out;

  char* wsb = (char*)d_ws;
  int*   flag = (int*)wsb;                                   // 256 B
  float* s    = (float*)(wsb + 256);                         // 131072 B
  float* wgt  = (float*)(wsb + 131328);                      // 261632 B (fallback only)
  __hip_bfloat16* Wts = (__hip_bfloat16*)(wsb + 393216);     // 524288 B
  __hip_bfloat16* xbf = (__hip_bfloat16*)(wsb + 917504);     // 32 MiB
  const size_t NEED = 917504 + 33554432;

  if (ws_size >= NEED) {
    prep<<<129, 256, 0, stream>>>((const unsigned char*)mask, flag, W, Wts);
    gemm_fused<<<512, 256, 0, stream>>>(x, Wts, bias, v, s, xbf);
    pool2<<<dim3(64, Bsz, 2), 256, 0, stream>>>(xbf, s, mask, flag, out);
  } else {
    detect_mask<<<1, 256, 0, stream>>>((const unsigned char*)mask, flag);
    gemm_s_f32<<<dim3(Lsz / 64, Bsz), 256, 0, stream>>>(x, W, bias, v, s);
    win_weights<<<(Bsz * LPOOL + 255) / 256, 256, 0, stream>>>(s, mask, flag, wgt);
    pool_out<<<Bsz * Csz, 256, 0, stream>>>(x, wgt, out);
  }
}